// Round 10
// baseline (121.898 us; speedup 1.0000x reference)
//
#include <hip/hip_runtime.h>
#include <math.h>

// fab_penalty_ls_curve — R13: 4 cols/thread (f32x4 window) + branchless atan.
// R12 post-mortem: total 108.4us best; partial ~34.2us; fixed overhead 74.2us
// (41us harness 256MB poison-fill @81% HBM — at ITS roofline — + launch/replay).
// rsqrt merge ~-1.3us (matched arith); ROWS_PER 32 neutral -> back to 16.
// R13 levers (last big one before the roofline call):
// (1) 4 cols/thread: loads 1.5->0.75/pt; rotation movs halved/pt; ALIGNED
//     pair structure makes eyw/eye formations free and shares the middle
//     term (eyw_hi == eye_lo, same registers). Why this won't repeat R5:
//     chain shrank state; B row carries wings only; unroll 2 caps hoisting
//     (~98 VGPR peak est, under the (256,4)=128 cap).
// (2) branchless packed atan: t = min(v,|c|)*rcp(max(v,|c|)), packed poly,
//     per-comp select + copysign — ~20 -> ~11 slots/pt. Same poly coeffs,
//     same ~1e-5 rad bound (1e3 below budget).
// Per-component formulas verified term-by-term == R12 (absmax 0.0 lineage);
// only the atan formulation differs (bounded).
// Tripwires: WRITE_SIZE ~128KB (spill); absmax. Two-kernel finish is settled
// law (R2/R3/R10: device-scope handshakes regress 2-3x on MI355X).
// Assumes Wn % (4*BLOCK_X) == 0 (4096x4096 input).

#define BLOCK_X 256
#define ROWS_PER 16

typedef float f32x2 __attribute__((ext_vector_type(2)));
typedef float f32x4 __attribute__((ext_vector_type(4)));

__device__ __forceinline__ f32x2 mk2(float a, float b) { f32x2 v; v.x = a; v.y = b; return v; }
__device__ __forceinline__ f32x2 sp2(float a) { return mk2(a, a); }

#if __has_builtin(__builtin_elementwise_fma)
__device__ __forceinline__ f32x2 fma2(f32x2 a, f32x2 b, f32x2 c) { return __builtin_elementwise_fma(a, b, c); }
#else
__device__ __forceinline__ f32x2 fma2(f32x2 a, f32x2 b, f32x2 c) { return mk2(fmaf(a.x, b.x, c.x), fmaf(a.y, b.y, c.y)); }
#endif
#if __has_builtin(__builtin_elementwise_max)
__device__ __forceinline__ f32x2 max2(f32x2 a, f32x2 b) { return __builtin_elementwise_max(a, b); }
__device__ __forceinline__ f32x2 min2(f32x2 a, f32x2 b) { return __builtin_elementwise_min(a, b); }
#else
__device__ __forceinline__ f32x2 max2(f32x2 a, f32x2 b) { return mk2(fmaxf(a.x, b.x), fmaxf(a.y, b.y)); }
__device__ __forceinline__ f32x2 min2(f32x2 a, f32x2 b) { return mk2(fminf(a.x, b.x), fminf(a.y, b.y)); }
#endif
__device__ __forceinline__ f32x2 abs2(f32x2 a) { return mk2(fabsf(a.x), fabsf(a.y)); }
__device__ __forceinline__ f32x2 rcp2(f32x2 a) { return mk2(__builtin_amdgcn_rcpf(a.x), __builtin_amdgcn_rcpf(a.y)); }

struct V4 { f32x2 lo, hi; };
__device__ __forceinline__ V4 mkv(f32x2 lo, f32x2 hi) { V4 r; r.lo = lo; r.hi = hi; return r; }
__device__ __forceinline__ V4 splat4(float x) { return mkv(sp2(x), sp2(x)); }
__device__ __forceinline__ V4 add4(V4 a, V4 b) { return mkv(a.lo + b.lo, a.hi + b.hi); }
__device__ __forceinline__ V4 sub4(V4 a, V4 b) { return mkv(a.lo - b.lo, a.hi - b.hi); }
__device__ __forceinline__ V4 mul4(V4 a, V4 b) { return mkv(a.lo * b.lo, a.hi * b.hi); }
__device__ __forceinline__ V4 muls(V4 a, float s) { return mkv(a.lo * s, a.hi * s); }
__device__ __forceinline__ V4 fma4(V4 a, V4 b, V4 c) { return mkv(fma2(a.lo, b.lo, c.lo), fma2(a.hi, b.hi, c.hi)); }
__device__ __forceinline__ V4 fmas(V4 a, f32x2 s, f32x2 c) { return mkv(fma2(a.lo, s, c), fma2(a.hi, s, c)); }
__device__ __forceinline__ V4 max4(V4 a, V4 b) { return mkv(max2(a.lo, b.lo), max2(a.hi, b.hi)); }
__device__ __forceinline__ V4 abs4(V4 a) { return mkv(abs2(a.lo), abs2(a.hi)); }

// Branchless packed atan(v/c), v > 0: t = min(v,|c|)*rcp(max(v,|c|)),
// poly(t), big => pi/2 - at0, sign from c. Same coeffs/bound as the verified
// fast_atan_ratio (~1e-5 rad).
__device__ __forceinline__ V4 atan4_bl(V4 v, V4 c)
{
    V4 a  = abs4(c);
    V4 mn = mkv(min2(v.lo, a.lo), min2(v.hi, a.hi));
    V4 mx = mkv(max2(v.lo, a.lo), max2(v.hi, a.hi));
    V4 r  = mkv(rcp2(mx.lo), rcp2(mx.hi));
    V4 t  = mul4(mn, r);
    V4 s  = mul4(t, t);
    V4 p  = fma4(s, splat4(-0.01172120f), splat4(0.05265332f));
    p = fma4(s, p, splat4(-0.11643287f));
    p = fma4(s, p, splat4( 0.19354346f));
    p = fma4(s, p, splat4(-0.33262347f));
    p = fma4(s, p, splat4( 0.99997726f));
    V4 at0 = mul4(p, t);
    const f32x2 P2 = sp2(1.57079632679f);
    V4 alt = mkv(P2 - at0.lo, P2 - at0.hi);
    V4 res;
    res.lo.x = copysignf((v.lo.x > a.lo.x) ? alt.lo.x : at0.lo.x, c.lo.x);
    res.lo.y = copysignf((v.lo.y > a.lo.y) ? alt.lo.y : at0.lo.y, c.lo.y);
    res.hi.x = copysignf((v.hi.x > a.hi.x) ? alt.hi.x : at0.hi.x, c.hi.x);
    res.hi.y = copysignf((v.hi.y > a.hi.y) ? alt.hi.y : at0.hi.y, c.hi.y);
    return res;
}

// scalar atan for the YB fallback path (R12-verified)
__device__ __forceinline__ float fast_atan_ratio(float v, float c, float rv)
{
    const float rc = __builtin_amdgcn_rcpf(c);
    const float q  = v * rc;
    const float iq = c * rv;
    const bool  big = fabsf(q) > 1.0f;
    const float t  = big ? iq : q;
    const float s  = t * t;
    float p = fmaf(s, -0.01172120f, 0.05265332f);
    p = fmaf(s, p, -0.11643287f);
    p = fmaf(s, p,  0.19354346f);
    p = fmaf(s, p, -0.33262347f);
    p = fmaf(s, p,  0.99997726f);
    const float at = p * t;
    const float hp = copysignf(1.57079632679f, q);
    return big ? (hp - at) : at;
}

// 8-wide row window (cols j0-2..j0+5): wings as f32x2, center as f32x4.
// XE blocks: clamp wing addresses in-bounds, then substitute values:
//   left  (j0==0):      cols -2,-1 -> {c0, c0}
//   right (j0+4==Wn):   cols Wn,Wn+1 mirror -> {c3, c2}
struct Row { f32x2 m, c0, c1, p; };

template<bool XE>
__device__ __forceinline__ void load8(const float* __restrict__ rowp, int j0,
                                      bool left, bool right, Row& R)
{
    const f32x4 cv = *reinterpret_cast<const f32x4*>(rowp + j0);
    R.c0 = mk2(cv.x, cv.y);
    R.c1 = mk2(cv.z, cv.w);
    if (XE) {
        const float* ma = rowp + (left  ? j0 : j0 - 2);
        const float* pa = rowp + (right ? j0 : j0 + 4);
        R.m = *reinterpret_cast<const f32x2*>(ma);
        R.p = *reinterpret_cast<const f32x2*>(pa);
        if (left)  R.m = mk2(cv.x, cv.x);
        if (right) R.p = mk2(cv.w, cv.z);
    } else {
        R.m = *reinterpret_cast<const f32x2*>(rowp + j0 - 2);
        R.p = *reinterpret_cast<const f32x2*>(rowp + j0 + 4);
    }
}

// Packed interior-Y strip, 4 cols {j0..j0+3}. Carried: B wings only (center
// lives in the gc chain), C/D/E full rows, chain xm1/x0/xp1 + gc0/gc1.
template<bool XE>
__device__ __forceinline__ V4 strip_packed4(
    const float* __restrict__ eps, int Wn, int i0, int j0,
    bool left, bool right, float rd, float rd2)
{
    const f32x2 SC2    = sp2(1e-12f);
    const float FLOORV = (float)(1e-32 / 6.0);
    const float pi_d   = 3.14159265358979323846f / 1.1f;
    const f32x2 rd2v   = sp2(rd2);
    const float rd2sq  = rd2 * rd2;
    // per-col scales (col0 may be the j==0 boundary; cols >=2 never are)
    const f32x2 syj_lo = mk2(left ? rd : rd2, rd2);
    const f32x2 sym_lo = mk2(rd2, left ? rd : rd2);
    const f32x2 sxy_lo = syj_lo * rd2;

    const float* r0 = eps + (size_t)(i0 - 2) * (size_t)Wn;
    const f32x4 Acv = *reinterpret_cast<const f32x4*>(r0 + j0);
    f32x2 Bm, Bp;
    Row C, D, E;
    V4 xm1, x0, xp1, gc0, gc1;
    {
        Row B;
        load8<XE>(r0 + (size_t)Wn,     j0, left, right, B);
        Bm = B.m; Bp = B.p;
        load8<XE>(r0 + (size_t)2 * Wn, j0, left, right, C);
        load8<XE>(r0 + (size_t)3 * Wn, j0, left, right, D);
        load8<XE>(r0 + (size_t)4 * Wn, j0, left, right, E);
        // chain init (bit-identical to R12's formulas)
        const V4 Ac   = mkv(mk2(Acv.x, Acv.y), mk2(Acv.z, Acv.w));
        const V4 Ccen = mkv(C.c0, C.c1);
        const V4 Bcen = mkv(B.c0, B.c1);
        const V4 Dcen = mkv(D.c0, D.c1);
        const V4 Ecen = mkv(E.c0, E.c1);
        gc0 = sub4(Dcen, Bcen);
        gc1 = sub4(Ecen, Ccen);
        xm1 = fmas(sub4(Ccen, Ac), rd2v, SC2);
        x0  = fmas(gc0, rd2v, SC2);
        xp1 = fmas(gc1, rd2v, SC2);
    }
    const float* pr = r0 + (size_t)5 * Wn;   // row i0+3

    V4 acc = splat4(0.0f);
    #pragma unroll 2
    for (int r = 0; r < ROWS_PER; ++r) {
        // prefetch row i+3 (3 loads: x2 + x4 + x2) before the compute
        Row F;
        load8<XE>(pr, j0, left, right, F);
        pr += Wn;

        const V4 gc2 = mkv(F.c0 - D.c0, F.c1 - D.c1);  // raw diff row i+2
        const V4 x2v = fmas(gc2, rd2v, SC2);           // eps_x(i+2)

        const V4 ex  = x0;
        const V4 exx = muls(sub4(xp1, xm1), rd2);

        // ey: cols j-1 / j+1 windows (Cl1.hi == Cr1.lo shared register)
        const V4 Cl1 = mkv(mk2(C.m.y, C.c0.x), mk2(C.c0.y, C.c1.x));
        const V4 Cr1 = mkv(Cl1.hi, mk2(C.c1.y, C.p.x));
        const V4 ey  = mkv(fma2(Cr1.lo - Cl1.lo, syj_lo, SC2),
                           fma2(Cr1.hi - Cl1.hi, rd2v,   SC2));

        // eyw/eye: aligned pairs; middle term shared (eyw_hi == eye_lo)
        const f32x2 midd  = fma2(C.c1 - C.c0, rd2v, SC2);
        f32x2 eyw_lo      = fma2(C.c0 - C.m, sym_lo, SC2);
        if (XE) { if (left) eyw_lo.x = ey.lo.x; }   // j==0: eps_y[jm]==eps_y[j]
        const f32x2 eye_hi = fma2(C.p - C.c1, rd2v, SC2);
        const V4 eyy = mkv((midd - eyw_lo) * syj_lo, (eye_hi - midd) * rd2);

        // exy from the gc chain + row-i wings (Gl1.hi == Gr1.lo shared)
        const f32x2 Gm = D.m - Bm, Gp = D.p - Bp;
        const V4 Gl1 = mkv(mk2(Gm.y, gc0.lo.x), mk2(gc0.lo.y, gc0.hi.x));
        const V4 Gr1 = mkv(Gl1.hi, mk2(gc0.hi.y, Gp.x));
        const V4 exy = mkv((Gr1.lo - Gl1.lo) * sxy_lo,
                           (Gr1.hi - Gl1.hi) * rd2sq);

        const V4 t1 = mul4(ex, ex), t2 = mul4(ey, ey);
        V4 num = mul4(t1, eyy);
        num = fma4(t2, exx, num);
        num = fma4(muls(mul4(ex, ey), -2.0f), exy, num);
        const V4 ssum = add4(t1, t2);
        const V4 rv = mkv(mk2(__builtin_amdgcn_rsqf(ssum.lo.x),
                              __builtin_amdgcn_rsqf(ssum.lo.y)),
                          mk2(__builtin_amdgcn_rsqf(ssum.hi.x),
                              __builtin_amdgcn_rsqf(ssum.hi.y)));
        V4 ev = mul4(ssum, rv);
        ev = max4(ev, splat4(FLOORV));
        const V4 k  = mul4(mul4(num, mul4(rv, rv)), rv);
        const V4 at = atan4_bl(ev, mkv(C.c0, C.c1));
        const V4 cc = sub4(abs4(mul4(k, at)), splat4(pi_d));
        acc = add4(acc, max4(cc, splat4(0.0f)));   // maxnum(NaN,0)=0 -> nansum

        // rotate (named registers; unroll 2 => ~half the movs renamed away)
        Bm = C.m; Bp = C.p;
        C = D; D = E; E = F;
        xm1 = x0; x0 = xp1; xp1 = x2v; gc0 = gc1; gc1 = gc2;
    }
    return acc;
}

// R12's verified generic scalar strip (row-clamped, all column cases).
__device__ float strip_scalar_yb(const float* __restrict__ eps, int Hn, int Wn,
                                 int i0, int j, float rd, float rd2)
{
    const float SC     = 1e-12f;
    const float FLOORV = (float)(1e-32 / 6.0);
    const float pi_d   = 3.14159265358979323846f / 1.1f;

    const int jm  = (j > 0) ? j - 1 : 0;
    const int jmm = (j > 1) ? j - 2 : 0;
    const int jp = j + 1, jpp = j + 2;
    const int cjp  = (jp  < Wn) ? jp  : (2 * Wn - 1 - jp);
    const int cjpp = (jpp < Wn) ? jpp : (2 * Wn - 1 - jpp);
    const bool jz = (j == 0);
    const float syj = jz ? rd : rd2;
    const float sym = (jm == 0) ? rd : rd2;

    auto rp = [&](int t) -> const float* {
        int tt = t < 0 ? 0 : t;
        tt = tt > Hn - 1 ? Hn - 1 : tt;
        return eps + (size_t)tt * (size_t)Wn;
    };

    float a2 = rp(i0 - 2)[j],   a1 = rp(i0 - 1)[j],  a0 = rp(i0)[j];
    float b1 = rp(i0 + 1)[j],   b2 = rp(i0 + 2)[j];
    float wN = rp(i0 - 1)[jm],  w0 = rp(i0)[jm],     wS = rp(i0 + 1)[jm];
    float eN = rp(i0 - 1)[cjp], e0 = rp(i0)[cjp],    eS = rp(i0 + 1)[cjp];
    float ww = rp(i0)[jmm],     ee = rp(i0)[cjpp];

    float acc = 0.0f;
    #pragma unroll 4
    for (int r = 0; r < ROWS_PER; ++r) {
        const int i = i0 + r;
        const float* q3 = rp(i + 3);
        const float* q2 = rp(i + 2);
        const float* q1 = rp(i + 1);
        const float nb2 = q3[j], nwS = q2[jm], neS = q2[cjp];
        const float nww = q1[jmm], nee = q1[cjpp];

        const bool itop = (i == 0), ibot = (i == Hn - 1);
        const float sxi = (itop || ibot) ? rd : rd2;
        const float sxm = (i == 1) ? rd : rd2;
        const float sxp = (i == Hn - 2) ? rd : rd2;

        const float ex = fmaf(b1 - a1, sxi, SC);
        const float ey = fmaf(e0 - w0, syj, SC);
        float exn = fmaf(a0 - a2, sxm, SC);
        float exs = fmaf(b2 - a0, sxp, SC);
        if (itop) exn = ex;
        if (ibot) exs = ex;
        const float exx = (exs - exn) * sxi;
        float eyw = fmaf(a0 - ww, sym, SC);
        const float eye = fmaf(ee - a0, rd2, SC);
        if (jz) eyw = ey;
        const float eyy = (eye - eyw) * syj;
        const float exy = ((eS - eN) - (wS - wN)) * (sxi * syj);

        const float t1 = ex * ex, t2 = ey * ey;
        float num = t1 * eyy;
        num = fmaf(t2, exx, num);
        num = fmaf(-2.0f * (ex * ey), exy, num);
        const float ssum = t1 + t2;
        const float rv = __builtin_amdgcn_rsqf(ssum);
        float ev = ssum * rv;
        ev = fmaxf(ev, FLOORV);
        const float k  = num * (rv * rv) * rv;
        const float at = fast_atan_ratio(ev, a0, rv);
        const float ccv = fabsf(k * at) - pi_d;
        float contrib = fmaxf(ccv, 0.0f);
        if (i >= Hn) contrib = 0.0f;
        acc += contrib;

        a2 = a1; a1 = a0; a0 = b1; b1 = b2; b2 = nb2;
        wN = w0; w0 = wS; wS = nwS;
        eN = e0; e0 = eS; eS = neS;
        ww = nww; ee = nee;
    }
    return acc;
}

__global__ __launch_bounds__(BLOCK_X, 4) void curve_partial_kernel(
    const float* __restrict__ eps, const float* __restrict__ gs,
    double* __restrict__ partial, int Hn, int Wn)
{
    const int tx = threadIdx.x;
    const int j0 = (blockIdx.x * BLOCK_X + tx) * 4;
    const int i0 = blockIdx.y * ROWS_PER;
    const float d   = gs[0];
    const float rd  = 1.0f / d;
    const float rd2 = 0.5f * rd;
    const bool left  = (j0 == 0);
    const bool right = (j0 + 4 == Wn);

    // interior path touches rows i0-2 .. i0+ROWS_PER+2 (incl. last prefetch)
    const bool yint = (i0 >= 2) && (i0 + ROWS_PER + 2 < Hn);

    V4 accv;
    if (yint) {
        const bool xe = (blockIdx.x == 0) || (blockIdx.x == gridDim.x - 1);
        accv = xe
            ? strip_packed4<true >(eps, Wn, i0, j0, left, right, rd, rd2)
            : strip_packed4<false>(eps, Wn, i0, j0, left, right, rd, rd2);
    } else {
        accv.lo = mk2(strip_scalar_yb(eps, Hn, Wn, i0, j0,     rd, rd2),
                      strip_scalar_yb(eps, Hn, Wn, i0, j0 + 1, rd, rd2));
        accv.hi = mk2(strip_scalar_yb(eps, Hn, Wn, i0, j0 + 2, rd, rd2),
                      strip_scalar_yb(eps, Hn, Wn, i0, j0 + 3, rd, rd2));
    }

    double acc = ((double)accv.lo.x + (double)accv.lo.y)
               + ((double)accv.hi.x + (double)accv.hi.y);
    #pragma unroll
    for (int off = 32; off > 0; off >>= 1)
        acc += __shfl_down(acc, off, 64);
    __shared__ double lds[BLOCK_X / 64];
    const int lane = tx & 63, wv = tx >> 6;
    if (lane == 0) lds[wv] = acc;
    __syncthreads();
    if (tx == 0) {
        // plain store — NO device-scope atomics/fences (R2/R3/R10 regressions)
        partial[blockIdx.y * gridDim.x + blockIdx.x] =
            lds[0] + lds[1] + lds[2] + lds[3];
    }
}

__global__ __launch_bounds__(256) void curve_finish_kernel(
    const double* __restrict__ partial, int n,
    const float* __restrict__ gs, float* __restrict__ out)
{
    const int tx = threadIdx.x;
    double acc = 0.0;
    for (int idx = tx; idx < n; idx += 256) acc += partial[idx];
    #pragma unroll
    for (int off = 32; off > 0; off >>= 1)
        acc += __shfl_down(acc, off, 64);
    __shared__ double lds[4];
    const int lane = tx & 63, wv = tx >> 6;
    if (lane == 0) lds[wv] = acc;
    __syncthreads();
    if (tx == 0) {
        const double dd = (double)gs[0];
        // x2 for the mirrored half; x d^2 for grid_size^2 (ALPHA=1)
        out[0] = (float)((lds[0] + lds[1] + lds[2] + lds[3]) * 2.0 * dd * dd);
    }
}

extern "C" void kernel_launch(void* const* d_in, const int* in_sizes, int n_in,
                              void* d_out, int out_size, void* d_ws, size_t ws_size,
                              hipStream_t stream) {
    const float* eps = (const float*)d_in[0];
    const float* gs  = (const float*)d_in[1];
    float* out = (float*)d_out;

    const int n = in_sizes[0];
    int Wn = (int)(sqrt((double)n) + 0.5);   // 4096 for 4096x4096
    int Hn = n / Wn;

    const int gx = Wn / (BLOCK_X * 4);               // 4 (assumes divisible)
    const int gy = (Hn + ROWS_PER - 1) / ROWS_PER;   // 256
    const int nb = gx * gy;                          // 1024
    double* partial = (double*)d_ws;   // nb slots, ALL written every launch

    curve_partial_kernel<<<dim3(gx, gy), BLOCK_X, 0, stream>>>(eps, gs, partial, Hn, Wn);
    curve_finish_kernel<<<1, 256, 0, stream>>>(partial, nb, gs, out);
}

// Round 11
// 108.828 us; speedup vs baseline: 1.1201x; 1.1201x over previous
//
#include <hip/hip_runtime.h>
#include <math.h>

// fab_penalty_ls_curve — R14: pure revert to R12 (best measured: 108.4us,
// absmax 0.0). R13 post-mortem: 4-col f32x4 window SPILLED exactly on the
// pre-stated tripwire (WRITE_SIZE 128KB -> 6.1MB, VGPR pinned 64, occupancy
// 22%, partial 34 -> 45-48us). Second independent confirmation (R5, R13)
// that 4 cols/thread is over the register wall — 2-col f32x2 is the sweet
// spot. Branchless atan also recounted: no net saving at 2-wide (poly was
// already packed; rcp(c) trades for abs/min/max/sub).
// Settled law this session:
//   - two-kernel plain-store finish (R2/R3/R10: device handshakes 2-3x worse)
//   - depth-limited unroll (R7: full unroll => scheduler hoists => spill)
//   - never cap launch_bounds below natural VGPR demand (R6)
//   - 2 cols/thread f32x2, eps_x/gc rolling chain, rsqrt merge (R9-R12 wins)
// Budget at R12: partial ~34.2us controllable + 74.2us fixed (41us harness
// 256MB poison-fill @81% HBM — its own roofline — + finish + launch gaps).
// If this reproduces ~108us, the session calls roofline next round.

#define BLOCK_X 256
#define ROWS_PER 32

typedef float f32x2 __attribute__((ext_vector_type(2)));

__device__ __forceinline__ f32x2 mk2(float a, float b) { f32x2 v; v.x = a; v.y = b; return v; }
__device__ __forceinline__ f32x2 sp2(float a) { return mk2(a, a); }

#if __has_builtin(__builtin_elementwise_fma)
__device__ __forceinline__ f32x2 fma2(f32x2 a, f32x2 b, f32x2 c) { return __builtin_elementwise_fma(a, b, c); }
#else
__device__ __forceinline__ f32x2 fma2(f32x2 a, f32x2 b, f32x2 c) { return mk2(fmaf(a.x, b.x, c.x), fmaf(a.y, b.y, c.y)); }
#endif
#if __has_builtin(__builtin_elementwise_max)
__device__ __forceinline__ f32x2 max2(f32x2 a, f32x2 b) { return __builtin_elementwise_max(a, b); }
#else
__device__ __forceinline__ f32x2 max2(f32x2 a, f32x2 b) { return mk2(fmaxf(a.x, b.x), fmaxf(a.y, b.y)); }
#endif
__device__ __forceinline__ f32x2 abs2(f32x2 a) { return mk2(fabsf(a.x), fabsf(a.y)); }

// ---- scalar helpers (YB path + per-component transcendentals) ----

// atan(v / c) with v > 0, given rv ~= 1/v. Max abs err ~1e-5 rad.
__device__ __forceinline__ float fast_atan_ratio(float v, float c, float rv)
{
    const float rc = __builtin_amdgcn_rcpf(c);
    const float q  = v * rc;
    const float iq = c * rv;
    const bool  big = fabsf(q) > 1.0f;
    const float t  = big ? iq : q;
    const float s  = t * t;
    float p = fmaf(s, -0.01172120f, 0.05265332f);
    p = fmaf(s, p, -0.11643287f);
    p = fmaf(s, p,  0.19354346f);
    p = fmaf(s, p, -0.33262347f);
    p = fmaf(s, p,  0.99997726f);
    const float at = p * t;
    const float hp = copysignf(1.57079632679f, q);
    return big ? (hp - at) : at;
}

// packed variant: componentwise identical op sequence
__device__ __forceinline__ f32x2 fast_atan_ratio2(f32x2 v, f32x2 c, f32x2 rvv)
{
    const f32x2 rc = mk2(__builtin_amdgcn_rcpf(c.x), __builtin_amdgcn_rcpf(c.y));
    const f32x2 q  = v * rc;
    const f32x2 iq = c * rvv;
    const bool big0 = fabsf(q.x) > 1.0f, big1 = fabsf(q.y) > 1.0f;
    const f32x2 t = mk2(big0 ? iq.x : q.x, big1 ? iq.y : q.y);
    const f32x2 s = t * t;
    f32x2 p = fma2(s, sp2(-0.01172120f), sp2(0.05265332f));
    p = fma2(s, p, sp2(-0.11643287f));
    p = fma2(s, p, sp2( 0.19354346f));
    p = fma2(s, p, sp2(-0.33262347f));
    p = fma2(s, p, sp2( 0.99997726f));
    const f32x2 at = p * t;
    const float hp0 = copysignf(1.57079632679f, q.x);
    const float hp1 = copysignf(1.57079632679f, q.y);
    return mk2(big0 ? (hp0 - at.x) : at.x, big1 ? (hp1 - at.y) : at.y);
}

// Load the 6-wide window (cols j0-2..j0+3) of one row as 3 aligned float2.
// XE blocks: clamp wing addresses in-bounds, then substitute values:
//   left  (j0==0):     cols -2,-1 clamp to col 0      -> {c.x, c.x}
//   right (j0+2==Wn):  cols Wn,Wn+1 mirror to Wn-1..  -> {c.y, c.x}
template<bool XE>
__device__ __forceinline__ void load6(const float* __restrict__ rowp, int j0,
                                      bool left, bool right,
                                      f32x2& m, f32x2& c, f32x2& p)
{
    c = *reinterpret_cast<const f32x2*>(rowp + j0);
    if (XE) {
        const float* ma = rowp + (left  ? j0 : j0 - 2);
        const float* pa = rowp + (right ? j0 : j0 + 2);
        m = *reinterpret_cast<const f32x2*>(ma);
        p = *reinterpret_cast<const f32x2*>(pa);
        if (left)  m = mk2(c.x, c.x);
        if (right) p = mk2(c.y, c.x);
    } else {
        m = *reinterpret_cast<const f32x2*>(rowp + j0 - 2);
        p = *reinterpret_cast<const f32x2*>(rowp + j0 + 2);
    }
}

// Packed interior-Y strip with eps_x chain. Rows i0..i0+ROWS_PER-1,
// cols {j0, j0+1}. Carried state:
//   Bm,Bp (wings row i-1), Cm,Cc,Cp (i), Dm,Dc,Dp (i+1), Em,Ec,Ep (i+2)
//   xm1,x0,xp1 = eps_x(i-1 / i / i+1);  gc0,gc1 = raw center diffs rows i,i+1
template<bool XE>
__device__ __forceinline__ f32x2 strip_packed(
    const float* __restrict__ eps, int Wn, int i0, int j0,
    bool left, bool right, float rd2, f32x2 syjv, f32x2 symv)
{
    const f32x2 SC2    = sp2(1e-12f);
    const float FLOORV = (float)(1e-32 / 6.0);
    const float pi_d   = 3.14159265358979323846f / 1.1f;
    const f32x2 rd2v   = sp2(rd2);
    const f32x2 sxy    = syjv * rd2;     // exy scale (loop-invariant)

    const float* r0 = eps + (size_t)(i0 - 2) * (size_t)Wn;
    const f32x2 Ac = *reinterpret_cast<const f32x2*>(r0 + j0);
    f32x2 Bm, Bc, Bp, Cm, Cc, Cp, Dm, Dc, Dp, Em, Ec, Ep;
    load6<XE>(r0 + (size_t)Wn,     j0, left, right, Bm, Bc, Bp);
    load6<XE>(r0 + (size_t)2 * Wn, j0, left, right, Cm, Cc, Cp);
    load6<XE>(r0 + (size_t)3 * Wn, j0, left, right, Dm, Dc, Dp);
    load6<XE>(r0 + (size_t)4 * Wn, j0, left, right, Em, Ec, Ep);
    const float* pr = r0 + (size_t)5 * Wn;   // row i0+3

    // chain init (bit-identical to R9's exn/ex/exs formulas)
    f32x2 xm1 = fma2(Cc - Ac, rd2v, SC2);    // eps_x(i0-1)
    f32x2 gc0 = Dc - Bc;                     // raw diff row i0
    f32x2 x0  = fma2(gc0, rd2v, SC2);        // eps_x(i0)
    f32x2 gc1 = Ec - Cc;                     // raw diff row i0+1
    f32x2 xp1 = fma2(gc1, rd2v, SC2);        // eps_x(i0+1)

    f32x2 acc = sp2(0.0f);
    #pragma unroll 4
    for (int r = 0; r < ROWS_PER; ++r) {
        // prefetch row i+3 (3 independent float2 loads) before the compute
        f32x2 Fm, Fc, Fp;
        load6<XE>(pr, j0, left, right, Fm, Fc, Fp);
        pr += Wn;

        const f32x2 gc2 = Fc - Dc;               // raw diff row i+2
        const f32x2 x2v = fma2(gc2, rd2v, SC2);  // eps_x(i+2)

        const f32x2 ex  = x0;
        const f32x2 exx = (xp1 - xm1) * rd2;
        const f32x2 Cl1 = mk2(Cm.y, Cc.x), Cr1 = mk2(Cc.y, Cp.x);
        const f32x2 ey  = fma2(Cr1 - Cl1, syjv, SC2);
        f32x2 eyw = fma2(Cc - Cm, symv, SC2);
        const f32x2 eye = fma2(Cp - Cc, rd2v, SC2);
        if (XE) { if (left) eyw.x = ey.x; }       // j==0: eps_y[jm]==eps_y[j]
        const f32x2 eyy = (eye - eyw) * syjv;
        const f32x2 Gm = Dm - Bm, Gp = Dp - Bp;   // wing diffs row i
        const f32x2 exyL = mk2(Gm.y, gc0.x), exyR = mk2(gc0.y, Gp.x);
        const f32x2 exy = (exyR - exyL) * sxy;

        const f32x2 t1 = ex * ex, t2 = ey * ey;
        f32x2 num = t1 * eyy;
        num = fma2(t2, exx, num);
        num = fma2((ex * ey) * -2.0f, exy, num);
        const f32x2 ssum = t1 + t2;
        // rsqrt merge: rv = rsq(ssum), ev = ssum*rv (saves one trans op)
        const f32x2 rvv = mk2(__builtin_amdgcn_rsqf(ssum.x),
                              __builtin_amdgcn_rsqf(ssum.y));
        f32x2 evv = ssum * rvv;
        evv = max2(evv, sp2(FLOORV));             // packed maxnum floor
        const f32x2 k   = num * (rvv * rvv) * rvv;
        const f32x2 at  = fast_atan_ratio2(evv, Cc, rvv);
        const f32x2 cc  = abs2(k * at) - sp2(pi_d);
        acc = acc + max2(cc, sp2(0.0f));          // maxnum(NaN,0)=0 -> nansum

        // rotate (named registers; unroll-4 => renaming, few real movs)
        xm1 = x0; x0 = xp1; xp1 = x2v; gc0 = gc1; gc1 = gc2;
        Bm = Cm; Bp = Cp;
        Cm = Dm; Cc = Dc; Cp = Dp;
        Dm = Em; Dc = Ec; Dp = Ep;
        Em = Fm; Ec = Fc; Ep = Fp;
    }
    (void)Bc;
    return acc;
}

// R8's verified scalar Y-boundary strip (YB hardwired true), one column.
__device__ float strip_scalar_yb(const float* __restrict__ eps, int Hn, int Wn,
                                 int i0, int j, float rd, float rd2)
{
    const float SC     = 1e-12f;
    const float FLOORV = (float)(1e-32 / 6.0);
    const float pi_d   = 3.14159265358979323846f / 1.1f;

    const int jm  = (j > 0) ? j - 1 : 0;
    const int jmm = (j > 1) ? j - 2 : 0;
    const int jp = j + 1, jpp = j + 2;
    const int cjp  = (jp  < Wn) ? jp  : (2 * Wn - 1 - jp);
    const int cjpp = (jpp < Wn) ? jpp : (2 * Wn - 1 - jpp);
    const bool jz = (j == 0);
    const float syj = jz ? rd : rd2;
    const float sym = (jm == 0) ? rd : rd2;

    auto rp = [&](int t) -> const float* {
        int tt = t < 0 ? 0 : t;
        tt = tt > Hn - 1 ? Hn - 1 : tt;
        return eps + (size_t)tt * (size_t)Wn;
    };

    float a2 = rp(i0 - 2)[j],   a1 = rp(i0 - 1)[j],  a0 = rp(i0)[j];
    float b1 = rp(i0 + 1)[j],   b2 = rp(i0 + 2)[j];
    float wN = rp(i0 - 1)[jm],  w0 = rp(i0)[jm],     wS = rp(i0 + 1)[jm];
    float eN = rp(i0 - 1)[cjp], e0 = rp(i0)[cjp],    eS = rp(i0 + 1)[cjp];
    float ww = rp(i0)[jmm],     ee = rp(i0)[cjpp];

    float acc = 0.0f;
    #pragma unroll 4
    for (int r = 0; r < ROWS_PER; ++r) {
        const int i = i0 + r;
        const float* q3 = rp(i + 3);
        const float* q2 = rp(i + 2);
        const float* q1 = rp(i + 1);
        const float nb2 = q3[j], nwS = q2[jm], neS = q2[cjp];
        const float nww = q1[jmm], nee = q1[cjpp];

        const bool itop = (i == 0), ibot = (i == Hn - 1);
        const float sxi = (itop || ibot) ? rd : rd2;
        const float sxm = (i == 1) ? rd : rd2;
        const float sxp = (i == Hn - 2) ? rd : rd2;

        const float ex = fmaf(b1 - a1, sxi, SC);
        const float ey = fmaf(e0 - w0, syj, SC);
        float exn = fmaf(a0 - a2, sxm, SC);
        float exs = fmaf(b2 - a0, sxp, SC);
        if (itop) exn = ex;
        if (ibot) exs = ex;
        const float exx = (exs - exn) * sxi;
        float eyw = fmaf(a0 - ww, sym, SC);
        const float eye = fmaf(ee - a0, rd2, SC);
        if (jz) eyw = ey;
        const float eyy = (eye - eyw) * syj;
        const float exy = ((eS - eN) - (wS - wN)) * (sxi * syj);

        const float t1 = ex * ex, t2 = ey * ey;
        float num = t1 * eyy;
        num = fmaf(t2, exx, num);
        num = fmaf(-2.0f * (ex * ey), exy, num);
        const float ssum = t1 + t2;
        // rsqrt merge (matches packed path)
        const float rv = __builtin_amdgcn_rsqf(ssum);
        float ev = ssum * rv;
        ev = fmaxf(ev, FLOORV);
        const float k  = num * (rv * rv) * rv;
        const float at = fast_atan_ratio(ev, a0, rv);
        const float ccv = fabsf(k * at) - pi_d;
        float contrib = fmaxf(ccv, 0.0f);
        if (i >= Hn) contrib = 0.0f;
        acc += contrib;

        a2 = a1; a1 = a0; a0 = b1; b1 = b2; b2 = nb2;
        wN = w0; w0 = wS; wS = nwS;
        eN = e0; e0 = eS; eS = neS;
        ww = nww; ee = nee;
    }
    return acc;
}

__global__ __launch_bounds__(BLOCK_X, 4) void curve_partial_kernel(
    const float* __restrict__ eps, const float* __restrict__ gs,
    double* __restrict__ partial, int Hn, int Wn)
{
    const int tx = threadIdx.x;
    const int j0 = (blockIdx.x * BLOCK_X + tx) * 2;
    const int i0 = blockIdx.y * ROWS_PER;
    const float d   = gs[0];
    const float rd  = 1.0f / d;
    const float rd2 = 0.5f * rd;
    const bool left  = (j0 == 0);
    const bool right = (j0 + 2 == Wn);

    // interior path touches rows i0-2 .. i0+ROWS_PER+2 (incl. last prefetch)
    const bool yint = (i0 >= 2) && (i0 + ROWS_PER + 2 < Hn);

    f32x2 accv;
    if (yint) {
        const f32x2 syjv = left ? mk2(rd,  rd2) : sp2(rd2);  // col0: fwd diff
        const f32x2 symv = left ? mk2(rd2, rd ) : sp2(rd2);  // col1: jm==0
        const bool xe = (blockIdx.x == 0) || (blockIdx.x == gridDim.x - 1);
        accv = xe
            ? strip_packed<true >(eps, Wn, i0, j0, left, right, rd2, syjv, symv)
            : strip_packed<false>(eps, Wn, i0, j0, left, right, rd2, syjv, symv);
    } else {
        accv.x = strip_scalar_yb(eps, Hn, Wn, i0, j0,     rd, rd2);
        accv.y = strip_scalar_yb(eps, Hn, Wn, i0, j0 + 1, rd, rd2);
    }

    double acc = (double)accv.x + (double)accv.y;
    #pragma unroll
    for (int off = 32; off > 0; off >>= 1)
        acc += __shfl_down(acc, off, 64);
    __shared__ double lds[BLOCK_X / 64];
    const int lane = tx & 63, wv = tx >> 6;
    if (lane == 0) lds[wv] = acc;
    __syncthreads();
    if (tx == 0) {
        // plain store — NO device-scope atomics/fences (R2/R3/R10 regressions)
        partial[blockIdx.y * gridDim.x + blockIdx.x] =
            lds[0] + lds[1] + lds[2] + lds[3];
    }
}

__global__ __launch_bounds__(256) void curve_finish_kernel(
    const double* __restrict__ partial, int n,
    const float* __restrict__ gs, float* __restrict__ out)
{
    const int tx = threadIdx.x;
    double acc = 0.0;
    for (int idx = tx; idx < n; idx += 256) acc += partial[idx];
    #pragma unroll
    for (int off = 32; off > 0; off >>= 1)
        acc += __shfl_down(acc, off, 64);
    __shared__ double lds[4];
    const int lane = tx & 63, wv = tx >> 6;
    if (lane == 0) lds[wv] = acc;
    __syncthreads();
    if (tx == 0) {
        const double dd = (double)gs[0];
        // x2 for the mirrored half; x d^2 for grid_size^2 (ALPHA=1)
        out[0] = (float)((lds[0] + lds[1] + lds[2] + lds[3]) * 2.0 * dd * dd);
    }
}

extern "C" void kernel_launch(void* const* d_in, const int* in_sizes, int n_in,
                              void* d_out, int out_size, void* d_ws, size_t ws_size,
                              hipStream_t stream) {
    const float* eps = (const float*)d_in[0];
    const float* gs  = (const float*)d_in[1];
    float* out = (float*)d_out;

    const int n = in_sizes[0];
    int Wn = (int)(sqrt((double)n) + 0.5);   // 4096 for 4096x4096
    int Hn = n / Wn;

    const int gx = Wn / (BLOCK_X * 2);               // 8 (assumes divisible)
    const int gy = (Hn + ROWS_PER - 1) / ROWS_PER;   // 128
    const int nb = gx * gy;                          // 1024
    double* partial = (double*)d_ws;   // nb slots, ALL written every launch

    curve_partial_kernel<<<dim3(gx, gy), BLOCK_X, 0, stream>>>(eps, gs, partial, Hn, Wn);
    curve_finish_kernel<<<1, 256, 0, stream>>>(partial, nb, gs, out);
}